// Round 12
// baseline (208.941 us; speedup 1.0000x reference)
//
#include <hip/hip_runtime.h>
#include <math.h>
#include <limits.h>

#define BB 8
#define NN 50000
#define NCH 32
#define CH32 1563                      // ceil(NN/32); last chunk short
#define EPSF 1.1920928955078125e-07f   // float32 machine eps
#define CEPS2 1.0e-6f                  // CHAR_EPS^2
#define QS   4194304.0f                // 2^22 fixed-point quantum for packed num
#define QINV (1.0f/4194304.0f)

// ---- ws layout (float offsets; ~5.6 MB total) ----
#define OFF_PARAMS 0        // 8*32 floats: [a, invP0..3, tf_pos, tf_neg, tl_pos, tl_neg, tmax, G0..3]
#define OFF_SUMS   256      // 256 floats (1KB, memset 0): f[0] evl, f[1] smooth; u32[2] final counter;
                            //   u32[16 + 16*b] per-batch arrival counters (64B apart)
#define OFF_FYMAX  512      // 32 floats (b*4+s)
#define OFF_MINMAX 328192   // int[8][32][4]
#define OFF_HIST   329216   // u32[8][32][512]
#define OFF_COFF   460288   // u32[8][32][512]
#define OFF_PRE    591360   // u32[8][520]: bins 0..511 excl-prefix, [512]=NN
#define OFF_DG     595520   // uint2[8][50000] sorted digest {f32 tb; x|y<<8|pol<<16}

#define SC_TOT   448        // scatter grid: 8 batches x 56 tiles (round-8 proven tiling)
#define SMOOTH_N 1392640

__device__ __forceinline__ unsigned long long encq(float v) {
    return (unsigned long long)((1LL << 40) + (long long)__float2int_rn(v * QS));
}

// valid on thread 0 only
__device__ __forceinline__ float block_reduce_sum(float v) {
    __shared__ float sm_[16];
    int lane = threadIdx.x & 63, wid = threadIdx.x >> 6;
    #pragma unroll
    for (int o = 32; o > 0; o >>= 1) v += __shfl_down(v, o);
    if (lane == 0) sm_[wid] = v;
    __syncthreads();
    float r = 0.0f;
    if (threadIdx.x == 0) {
        int nw = blockDim.x >> 6;
        for (int i = 0; i < nw; ++i) r += sm_[i];
    }
    __syncthreads();
    return r;
}

__device__ __forceinline__ float block_reduce_max(float v) {
    __shared__ float smx[16];
    int lane = threadIdx.x & 63, wid = threadIdx.x >> 6;
    #pragma unroll
    for (int o = 32; o > 0; o >>= 1) v = fmaxf(v, __shfl_down(v, o));
    if (lane == 0) smx[wid] = v;
    __syncthreads();
    float r = 0.0f;
    if (threadIdx.x == 0) {
        int nw = blockDim.x >> 6;
        for (int i = 0; i < nw; ++i) r = fmaxf(r, smx[i]);
    }
    __syncthreads();
    return r;
}

__device__ __forceinline__ float charb_fast(float d) {
    return __expf(0.45f * __logf(d * d + CEPS2));
}

// pass 1 (544 blocks): [0,256) per-(b,chunk) hist+minmax | [256,288) fy-max | [288,544) smoothness.
// The LAST-arriving block of each batch (of its 36 = 32 hist + 4 fymax) computes
// params + guards + bin prefix + per-chunk offsets (overlapped with remaining pass1 work).
__global__ __launch_bounds__(1024) void pass1_kernel(const float* __restrict__ ev,
                            const float* __restrict__ f0, const float* __restrict__ f1,
                            const float* __restrict__ f2, const float* __restrict__ f3,
                            float* __restrict__ ws) {
    int bi = blockIdx.x, tid = threadIdx.x;
    int myBatch = -1;
    if (bi < 256) {
        int b = bi >> 5, c = bi & 31;
        myBatch = b;
        const float* ey = ev + ((size_t)b * 4 + 1) * NN;
        const float* ep = ev + ((size_t)b * 4 + 3) * NN;
        __shared__ unsigned hist[512];
        __shared__ int s0[1024], s1[1024], s2[1024], s3[1024];
        for (int i = tid; i < 512; i += 1024) hist[i] = 0;
        __syncthreads();
        int minp = INT_MAX, maxp = -1, minn = INT_MAX, maxn = -1;
        int start = c * CH32, end = min(start + CH32, NN);
        for (int n = start + tid; n < end; n += 1024) {
            int yv = (int)ey[n];
            bool pos = (ep[n] == 1.0f);
            atomicAdd(&hist[(pos ? 0 : 256) + yv], 1u);
            if (pos) { minp = min(minp, n); maxp = max(maxp, n); }
            else     { minn = min(minn, n); maxn = max(maxn, n); }
        }
        s0[tid] = minp; s1[tid] = maxp; s2[tid] = minn; s3[tid] = maxn;
        __syncthreads();
        for (int o = 512; o > 0; o >>= 1) {
            if (tid < o) {
                s0[tid] = min(s0[tid], s0[tid + o]);
                s1[tid] = max(s1[tid], s1[tid + o]);
                s2[tid] = min(s2[tid], s2[tid + o]);
                s3[tid] = max(s3[tid], s3[tid + o]);
            }
            __syncthreads();
        }
        unsigned* gh = (unsigned*)(ws + OFF_HIST) + ((b << 5) + c) * 512;
        for (int i = tid; i < 512; i += 1024) gh[i] = hist[i];
        if (tid == 0) {
            int* mm = (int*)(ws + OFF_MINMAX) + ((b << 5) + c) * 4;
            mm[0] = s0[0]; mm[1] = s1[0]; mm[2] = s2[0]; mm[3] = s3[0];
        }
    } else if (bi < 288) {
        int k = bi - 256;
        int b = k >> 2, s = k & 3;
        myBatch = b;
        const float* fy;
        int hw;
        if (s == 0)      { fy = f0 + ((size_t)b * 2 + 1) * 1024;  hw = 1024; }
        else if (s == 1) { fy = f1 + ((size_t)b * 2 + 1) * 4096;  hw = 4096; }
        else if (s == 2) { fy = f2 + ((size_t)b * 2 + 1) * 16384; hw = 16384; }
        else             { fy = f3 + ((size_t)b * 2 + 1) * 65536; hw = 65536; }
        float m = 0.0f;
        for (int i = tid; i < hw; i += 1024) m = fmaxf(m, fabsf(fy[i]));
        float r = block_reduce_max(m);
        if (tid == 0) ws[OFF_FYMAX + k] = r;
    } else {
        int sb = bi - 288;            // [0,256)
        int stride = 256 * 1024;
        float acc = 0.0f;
        for (int j = sb * 1024 + tid; j < SMOOTH_N; j += stride) {
            const float* F; int jj, lg, lw;
            if (j < 16384)       { F = f0; jj = j;          lg = 10; lw = 5; }
            else if (j < 81920)  { F = f1; jj = j - 16384;  lg = 12; lw = 6; }
            else if (j < 344064) { F = f2; jj = j - 81920;  lg = 14; lw = 7; }
            else                 { F = f3; jj = j - 344064; lg = 16; lw = 8; }
            int hw = 1 << lg;
            int w  = 1 << lw;
            int plane = jj >> lg;
            int pix   = jj & (hw - 1);
            int yy = pix >> lw, xx = pix & (w - 1);
            const float* Fp = F + ((size_t)plane << lg);
            float v = Fp[pix];
            bool yok = (yy < w - 1), xok = (xx < w - 1);
            float inv_e = 0.5f / (16.0f * (float)(w - 1) * (float)w);
            float inv_d = 0.5f / (16.0f * (float)(w - 1) * (float)(w - 1));
            if (yok) { float d = Fp[pix + w] - v;     acc += charb_fast(d) * inv_e; }
            if (xok) { float d = Fp[pix + 1] - v;     acc += charb_fast(d) * inv_e; }
            if (yok && xok) {
                float d  = Fp[pix + w + 1] - v;       acc += charb_fast(d)  * inv_d;
                float d2 = Fp[pix + 1] - Fp[pix + w]; acc += charb_fast(d2) * inv_d;
            }
        }
        float r = block_reduce_sum(acc);
        if (tid == 0) atomicAdd(ws + OFF_SUMS + 1, r);   // sums zeroed by memsetAsync
    }

    // ---- fused prefix: last-arriving block of each batch does params+prefix ----
    if (myBatch < 0) return;
    __shared__ unsigned arrive;
    __threadfence();
    if (tid == 0) {
        unsigned* bc = (unsigned*)(ws + OFF_SUMS) + 16 + 16 * myBatch;
        arrive = atomicAdd(bc, 1u);
    }
    __syncthreads();
    if (arrive != 35) return;
    __threadfence();

    int b = myBatch;
    float* pp = ws + OFF_PARAMS + b * 32;
    if (tid == 0) {
        const int* mm = (const int*)(ws + OFF_MINMAX) + (b << 5) * 4;
        int mp = INT_MAX, xp = -1, mn = INT_MAX, xn = -1;
        for (int c = 0; c < 32; ++c) {
            mp = min(mp, mm[c * 4 + 0]); xp = max(xp, mm[c * 4 + 1]);
            mn = min(mn, mm[c * 4 + 2]); xn = max(xn, mm[c * 4 + 3]);
        }
        if (xp < 0) { mp = 0; xp = NN - 1; }   // argmax(all-false)==0 semantics
        if (xn < 0) { mn = 0; xn = NN - 1; }
        const float* t = ev + ((size_t)b * 4 + 2) * NN;
        float a = t[0], tlast = t[NN - 1];
        float d0 = tlast - a + EPSF;
        float P  = d0;
        float r  = (tlast - a) / d0;
        pp[0] = a;
        pp[1] = 1.0f / P;
        for (int i = 1; i < 4; ++i) {
            float d = r + EPSF;
            P *= d;
            r  = r / d;
            pp[1 + i] = 1.0f / P;
        }
        pp[5] = t[mp]; pp[6] = t[mn]; pp[7] = t[xp]; pp[8] = t[xn];
        float tmax = tlast - a;
        pp[9] = tmax;
        for (int s = 0; s < 4; ++s) {
            float invP = pp[1 + s];
            float T = 0.0f;
            for (int pol = 0; pol < 2; ++pol) {
                float tf = pp[5 + pol] - a, tl = pp[7 + pol] - a;
                float b0 = tl * invP + EPSF;
                float b1 = tf * invP - EPSF;
                T = fmaxf(T, fmaxf(fabsf(b0), fabsf(b0 - tmax * invP)));
                T = fmaxf(T, fmaxf(fabsf(b1), fabsf(b1 - tmax * invP)));
            }
            pp[10 + s] = (float)((int)ceilf(T * ws[OFF_FYMAX + b * 4 + s]) + 1);
        }
    }
    __syncthreads();
    __shared__ unsigned tot[512], bincnt[512];
    if (tid < 512) {
        unsigned run = 0;
        for (int c = 0; c < 32; ++c) {
            const unsigned* gh = (const unsigned*)(ws + OFF_HIST) + ((b << 5) + c) * 512;
            unsigned* gc = (unsigned*)(ws + OFF_COFF) + ((b << 5) + c) * 512;
            gc[tid] = run;
            run += gh[tid];
        }
        bincnt[tid] = run;
        tot[tid] = run;
    }
    __syncthreads();
    for (int o = 1; o < 512; o <<= 1) {
        unsigned v = 0;
        if (tid < 512 && tid >= o) v = tot[tid - o];
        __syncthreads();
        if (tid < 512 && tid >= o) tot[tid] += v;
        __syncthreads();
    }
    if (tid < 512) {
        unsigned Pex = tot[tid] - bincnt[tid];
        unsigned* gp = (unsigned*)(ws + OFF_PRE) + b * 520;
        gp[tid] = Pex;
        if (tid == 511) gp[512] = tot[511];   // == NN
        for (int c = 0; c < 32; ++c) {
            unsigned* gc = (unsigned*)(ws + OFF_COFF) + ((b << 5) + c) * 512;
            gc[tid] += Pex;
        }
    }
}

// pass 2 (256 blocks): write digest sorted by (pol, y)
__global__ __launch_bounds__(1024) void sortwrite_kernel(const float* __restrict__ ev, float* __restrict__ ws) {
    int b = blockIdx.x >> 5, c = blockIdx.x & 31;
    const float* ex = ev + (size_t)b * 4 * NN;
    const float* ey = ex + NN;
    const float* et = ex + 2 * NN;
    const float* ep = ex + 3 * NN;
    __shared__ unsigned cur[512];
    const unsigned* gc = (const unsigned*)(ws + OFF_COFF) + ((b << 5) + c) * 512;
    for (int i = threadIdx.x; i < 512; i += 1024) cur[i] = gc[i];
    __syncthreads();
    float a = et[0];
    uint2* dg = (uint2*)(ws + OFF_DG) + (size_t)b * NN;
    int start = c * CH32, end = min(start + CH32, NN);
    for (int n = start + threadIdx.x; n < end; n += 1024) {
        float x = ex[n], y = ey[n], tt = et[n], p = ep[n];
        int yv = (int)y;
        int pol = (p == 1.0f) ? 0 : 1;
        unsigned idx = atomicAdd(&cur[(pol << 8) + yv], 1u);
        uint2 d;
        d.x = __float_as_uint(tt - a);
        d.y = (unsigned)(int)x | ((unsigned)yv << 8) | ((unsigned)pol << 16);
        dg[idx] = d;
    }
}

// pass 3 (448 blocks): round-8 scatter tiling. For s0/s1 full-scan tiles, use CHUNKED
// per-lane event assignment: lane walks its own contiguous run, so a wave's 64 lanes
// sit far apart in y-sorted order -> different LDS rows -> same-address atomic
// serialization collapses (order change only; integer LDS adds commute).
__global__ __launch_bounds__(1024) void scatter_kernel(const float* __restrict__ f0,
                            const float* __restrict__ f1, const float* __restrict__ f2,
                            const float* __restrict__ f3, float* __restrict__ ws,
                            float* __restrict__ out) {
    __shared__ unsigned long long lds[8192];   // 64 KB max
    unsigned* cnts = (unsigned*)(ws + OFF_SUMS);
    int b    = blockIdx.x & 7;
    int tile = blockIdx.x >> 3;
    int tid  = threadIdx.x;
    int scale, c4, lo, nrows, w, sh;
    const float* fl;
    if (tile < 4)       { scale = 0; c4 = tile;      lo = 0;             nrows = 32; w = 32;  sh = 3; fl = f0; }
    else if (tile < 8)  { scale = 1; c4 = tile - 4;  lo = 0;             nrows = 64; w = 64;  sh = 2; fl = f1; }
    else if (tile < 24) { int g = tile - 8;  scale = 2; c4 = g >> 2; lo = (g & 3) * 32; nrows = 32; w = 128; sh = 1; fl = f2; }
    else                { int g = tile - 24; scale = 3; c4 = g >> 3; lo = (g & 7) * 32; nrows = 32; w = 256; sh = 0; fl = f3; }
    int pol = c4 >> 1, sgn = c4 & 1;
    int hw = w * w;
    int ncell = nrows * w;

    for (int i = tid; i < ncell / 2; i += 1024)
        ((ulonglong2*)lds)[i] = make_ulonglong2(0ULL, 0ULL);
    __syncthreads();

    const float* pp = ws + OFF_PARAMS + b * 32;
    float a    = pp[0];
    float invP = pp[1 + scale];
    float edge = (sgn == 0) ? (pp[7 + pol] - a) : (pp[5 + pol] - a);
    float base_t = edge * invP + ((sgn == 0) ? EPSF : -EPSF);
    fl += (size_t)b * 2 * hw;

    int ylo = 0, yhi = 255;
    if (scale >= 2) {
        int G = (int)pp[10 + scale];
        ylo = max((lo - G) << sh, 0);
        yhi = min(((lo + nrows - 1 + G) << sh) + ((1 << sh) - 1), 255);
    }
    const unsigned* gp = (const unsigned*)(ws + OFF_PRE) + b * 520 + (pol << 8);
    int r0 = (int)gp[ylo], r1 = (int)gp[yhi + 1];

    const uint2* dg = ((const uint2*)(ws + OFF_DG)) + (size_t)b * NN;
    float wm1 = (float)(w - 1);

    int nStart, nEnd, nStep;
    if (scale < 2) {   // chunked per-lane: contiguous run per thread
        int len = r1 - r0;
        int chunk = (len + 1023) >> 10;
        nStart = r0 + tid * chunk;
        nEnd = min(nStart + chunk, r1);
        nStep = 1;
    } else {           // banded tiles: strided (coalesced), rows already spread by x-width
        nStart = r0 + tid;
        nEnd = r1;
        nStep = 1024;
    }

    for (int n = nStart; n < nEnd; n += nStep) {
        uint2 d = dg[n];
        float tb = __uint_as_float(d.x);
        int xi = (int)(d.y & 255u) >> sh;
        int yi = (int)((d.y >> 8) & 255u) >> sh;
        float fx = fl[yi * w + xi];
        float fy = fl[hw + yi * w + xi];
        float t_ = base_t - tb * invP;
        float x_ = fminf(fmaxf((float)xi + t_ * fx, 0.0f), wm1);
        float y_ = fminf(fmaxf((float)yi + t_ * fy, 0.0f), wm1);
        float x0 = floorf(x_), x1 = ceilf(x_);
        float y0 = floorf(y_), y1 = ceilf(y_);
        float x0r = 1.0f - (x_ - x0), x1r = 1.0f - (x1 - x_);
        float y0r = 1.0f - (y_ - y0), y1r = 1.0f - (y1 - y_);
        int ix0 = (int)x0, ix1 = (int)x1;
        int rr0 = (int)y0 - lo, rr1 = (int)y1 - lo;
        if (rr0 >= 0 && rr0 < nrows) {
            atomicAdd(&lds[rr0 * w + ix0], encq((x0r * y0r + EPSF) * t_));
            atomicAdd(&lds[rr0 * w + ix1], encq((x1r * y0r + EPSF) * t_));
        }
        if (rr1 >= 0 && rr1 < nrows) {
            atomicAdd(&lds[rr1 * w + ix0], encq((x0r * y1r + EPSF) * t_));
            atomicAdd(&lds[rr1 * w + ix1], encq((x1r * y1r + EPSF) * t_));
        }
    }
    __syncthreads();

    float acc = 0.0f;
    for (int i = tid; i < ncell; i += 1024) {
        unsigned long long A = lds[i];
        if (!A) continue;
        unsigned long long cnt = (A + (1ULL << 39)) >> 40;
        long long sq = (long long)(A - (cnt << 40));
        float num = (float)sq * QINV;
        float v = num / ((float)cnt + EPSF);
        acc += v * v;
    }
    float r = block_reduce_sum(acc);

    if (tid == 0) {
        atomicAdd(ws + OFF_SUMS, r);
        __threadfence();
        unsigned old = atomicAdd(&cnts[2], 1u);
        if (old == SC_TOT - 1) {
            float evl = atomicAdd(ws + OFF_SUMS, 0.0f);
            float sm  = atomicAdd(ws + OFF_SUMS + 1, 0.0f);
            out[0] = evl + sm;
            out[1] = evl;
            out[2] = sm;
        }
    }
}

extern "C" void kernel_launch(void* const* d_in, const int* in_sizes, int n_in,
                              void* d_out, int out_size, void* d_ws, size_t ws_size,
                              hipStream_t stream) {
    const float* ev = (const float*)d_in[0];
    const float* f0 = (const float*)d_in[1];
    const float* f1 = (const float*)d_in[2];
    const float* f2 = (const float*)d_in[3];
    const float* f3 = (const float*)d_in[4];
    float* ws  = (float*)d_ws;
    float* out = (float*)d_out;

    // zero sums + counters (1 KB at float offset 256)
    hipMemsetAsync((char*)d_ws + OFF_SUMS * sizeof(float), 0, 1024, stream);
    pass1_kernel<<<544, 1024, 0, stream>>>(ev, f0, f1, f2, f3, ws);
    sortwrite_kernel<<<256, 1024, 0, stream>>>(ev, ws);
    scatter_kernel<<<SC_TOT, 1024, 0, stream>>>(f0, f1, f2, f3, ws, out);
}

// Round 13
// 124.472 us; speedup vs baseline: 1.6786x; 1.6786x over previous
//
#include <hip/hip_runtime.h>
#include <math.h>
#include <limits.h>

#define BB 8
#define NN 50000
#define NCH 32
#define CH32 1563                      // ceil(NN/32); last chunk short
#define EPSF 1.1920928955078125e-07f   // float32 machine eps
#define CEPS2 1.0e-6f                  // CHAR_EPS^2
#define QS   4194304.0f                // 2^22 fixed-point quantum for packed num
#define QINV (1.0f/4194304.0f)

// ---- ws layout (float offsets; ~5.6 MB total) ----
#define OFF_PARAMS 0        // 8*32 floats: [a, invP0..3, tf_pos, tf_neg, tl_pos, tl_neg, tmax, G0..3]
#define OFF_SUMS   256      // f[0] evl, f[1] smooth; u32[2] completion counter (memset to 0)
#define OFF_FYMAX  384      // 32 floats (b*4+s)
#define OFF_MINMAX 328192   // int[8][32][4]
#define OFF_HIST   329216   // u32[8][32][512]
#define OFF_COFF   460288   // u32[8][32][512]
#define OFF_PRE    591360   // u32[8][520]: bins 0..511 excl-prefix, [512]=NN
#define OFF_DG     595520   // uint2[8][50000] sorted digest {f32 tb; x|y<<8|pol<<16}

#define SC_TOT   512        // 8 batches x 64 tiles (s0/s1 y-banded, s2/s3 as round 8)
#define SMOOTH_N 1392640

__device__ __forceinline__ unsigned long long encq(float v) {
    return (unsigned long long)((1LL << 40) + (long long)__float2int_rn(v * QS));
}

// valid on thread 0 only
__device__ __forceinline__ float block_reduce_sum(float v) {
    __shared__ float sm_[16];
    int lane = threadIdx.x & 63, wid = threadIdx.x >> 6;
    #pragma unroll
    for (int o = 32; o > 0; o >>= 1) v += __shfl_down(v, o);
    if (lane == 0) sm_[wid] = v;
    __syncthreads();
    float r = 0.0f;
    if (threadIdx.x == 0) {
        int nw = blockDim.x >> 6;
        for (int i = 0; i < nw; ++i) r += sm_[i];
    }
    __syncthreads();
    return r;
}

__device__ __forceinline__ float block_reduce_max(float v) {
    __shared__ float smx[16];
    int lane = threadIdx.x & 63, wid = threadIdx.x >> 6;
    #pragma unroll
    for (int o = 32; o > 0; o >>= 1) v = fmaxf(v, __shfl_down(v, o));
    if (lane == 0) smx[wid] = v;
    __syncthreads();
    float r = 0.0f;
    if (threadIdx.x == 0) {
        int nw = blockDim.x >> 6;
        for (int i = 0; i < nw; ++i) r = fmaxf(r, smx[i]);
    }
    __syncthreads();
    return r;
}

__device__ __forceinline__ float charb_fast(float d) {
    return __expf(0.45f * __logf(d * d + CEPS2));
}

// pass 1 (544 blocks): [0,256) per-(b,chunk) hist+minmax | [256,288) fy-max | [288,544) smoothness
__global__ __launch_bounds__(1024) void pass1_kernel(const float* __restrict__ ev,
                            const float* __restrict__ f0, const float* __restrict__ f1,
                            const float* __restrict__ f2, const float* __restrict__ f3,
                            float* __restrict__ ws) {
    int bi = blockIdx.x, tid = threadIdx.x;
    if (bi < 256) {
        int b = bi >> 5, c = bi & 31;
        const float* ey = ev + ((size_t)b * 4 + 1) * NN;
        const float* ep = ev + ((size_t)b * 4 + 3) * NN;
        __shared__ unsigned hist[512];
        __shared__ int s0[1024], s1[1024], s2[1024], s3[1024];
        for (int i = tid; i < 512; i += 1024) hist[i] = 0;
        __syncthreads();
        int minp = INT_MAX, maxp = -1, minn = INT_MAX, maxn = -1;
        int start = c * CH32, end = min(start + CH32, NN);
        for (int n = start + tid; n < end; n += 1024) {
            int yv = (int)ey[n];
            bool pos = (ep[n] == 1.0f);
            atomicAdd(&hist[(pos ? 0 : 256) + yv], 1u);
            if (pos) { minp = min(minp, n); maxp = max(maxp, n); }
            else     { minn = min(minn, n); maxn = max(maxn, n); }
        }
        s0[tid] = minp; s1[tid] = maxp; s2[tid] = minn; s3[tid] = maxn;
        __syncthreads();
        for (int o = 512; o > 0; o >>= 1) {
            if (tid < o) {
                s0[tid] = min(s0[tid], s0[tid + o]);
                s1[tid] = max(s1[tid], s1[tid + o]);
                s2[tid] = min(s2[tid], s2[tid + o]);
                s3[tid] = max(s3[tid], s3[tid + o]);
            }
            __syncthreads();
        }
        unsigned* gh = (unsigned*)(ws + OFF_HIST) + ((b << 5) + c) * 512;
        for (int i = tid; i < 512; i += 1024) gh[i] = hist[i];
        if (tid == 0) {
            int* mm = (int*)(ws + OFF_MINMAX) + ((b << 5) + c) * 4;
            mm[0] = s0[0]; mm[1] = s1[0]; mm[2] = s2[0]; mm[3] = s3[0];
        }
    } else if (bi < 288) {
        int k = bi - 256;
        int b = k >> 2, s = k & 3;
        const float* fy;
        int hw;
        if (s == 0)      { fy = f0 + ((size_t)b * 2 + 1) * 1024;  hw = 1024; }
        else if (s == 1) { fy = f1 + ((size_t)b * 2 + 1) * 4096;  hw = 4096; }
        else if (s == 2) { fy = f2 + ((size_t)b * 2 + 1) * 16384; hw = 16384; }
        else             { fy = f3 + ((size_t)b * 2 + 1) * 65536; hw = 65536; }
        float m = 0.0f;
        for (int i = tid; i < hw; i += 1024) m = fmaxf(m, fabsf(fy[i]));
        float r = block_reduce_max(m);
        if (tid == 0) ws[OFF_FYMAX + k] = r;
    } else {
        int sb = bi - 288;            // [0,256)
        int stride = 256 * 1024;
        float acc = 0.0f;
        for (int j = sb * 1024 + tid; j < SMOOTH_N; j += stride) {
            const float* F; int jj, lg, lw;
            if (j < 16384)       { F = f0; jj = j;          lg = 10; lw = 5; }
            else if (j < 81920)  { F = f1; jj = j - 16384;  lg = 12; lw = 6; }
            else if (j < 344064) { F = f2; jj = j - 81920;  lg = 14; lw = 7; }
            else                 { F = f3; jj = j - 344064; lg = 16; lw = 8; }
            int hw = 1 << lg;
            int w  = 1 << lw;
            int plane = jj >> lg;
            int pix   = jj & (hw - 1);
            int yy = pix >> lw, xx = pix & (w - 1);
            const float* Fp = F + ((size_t)plane << lg);
            float v = Fp[pix];
            bool yok = (yy < w - 1), xok = (xx < w - 1);
            float inv_e = 0.5f / (16.0f * (float)(w - 1) * (float)w);
            float inv_d = 0.5f / (16.0f * (float)(w - 1) * (float)(w - 1));
            if (yok) { float d = Fp[pix + w] - v;     acc += charb_fast(d) * inv_e; }
            if (xok) { float d = Fp[pix + 1] - v;     acc += charb_fast(d) * inv_e; }
            if (yok && xok) {
                float d  = Fp[pix + w + 1] - v;       acc += charb_fast(d)  * inv_d;
                float d2 = Fp[pix + 1] - Fp[pix + w]; acc += charb_fast(d2) * inv_d;
            }
        }
        float r = block_reduce_sum(acc);
        if (tid == 0) atomicAdd(ws + OFF_SUMS + 1, r);   // sums zeroed by memsetAsync
    }
}

// pass 2 (8 blocks): params + guards + bin prefix + per-chunk offsets
__global__ __launch_bounds__(1024) void prefix_kernel(const float* __restrict__ ev, float* __restrict__ ws) {
    int b = blockIdx.x, tid = threadIdx.x;
    float* pp = ws + OFF_PARAMS + b * 32;
    if (tid == 0) {
        const int* mm = (const int*)(ws + OFF_MINMAX) + (b << 5) * 4;
        int mp = INT_MAX, xp = -1, mn = INT_MAX, xn = -1;
        for (int c = 0; c < 32; ++c) {
            mp = min(mp, mm[c * 4 + 0]); xp = max(xp, mm[c * 4 + 1]);
            mn = min(mn, mm[c * 4 + 2]); xn = max(xn, mm[c * 4 + 3]);
        }
        if (xp < 0) { mp = 0; xp = NN - 1; }   // argmax(all-false)==0 semantics
        if (xn < 0) { mn = 0; xn = NN - 1; }
        const float* t = ev + ((size_t)b * 4 + 2) * NN;
        float a = t[0], tlast = t[NN - 1];
        float d0 = tlast - a + EPSF;
        float P  = d0;
        float r  = (tlast - a) / d0;
        pp[0] = a;
        pp[1] = 1.0f / P;
        for (int i = 1; i < 4; ++i) {
            float d = r + EPSF;
            P *= d;
            r  = r / d;
            pp[1 + i] = 1.0f / P;
        }
        pp[5] = t[mp]; pp[6] = t[mn]; pp[7] = t[xp]; pp[8] = t[xn];
        float tmax = tlast - a;
        pp[9] = tmax;
        for (int s = 0; s < 4; ++s) {
            float invP = pp[1 + s];
            float T = 0.0f;
            for (int pol = 0; pol < 2; ++pol) {
                float tf = pp[5 + pol] - a, tl = pp[7 + pol] - a;
                float b0 = tl * invP + EPSF;
                float b1 = tf * invP - EPSF;
                T = fmaxf(T, fmaxf(fabsf(b0), fabsf(b0 - tmax * invP)));
                T = fmaxf(T, fmaxf(fabsf(b1), fabsf(b1 - tmax * invP)));
            }
            pp[10 + s] = (float)((int)ceilf(T * ws[OFF_FYMAX + b * 4 + s]) + 1);
        }
    }
    __syncthreads();
    __shared__ unsigned tot[512], bincnt[512];
    if (tid < 512) {
        unsigned run = 0;
        for (int c = 0; c < 32; ++c) {
            const unsigned* gh = (const unsigned*)(ws + OFF_HIST) + ((b << 5) + c) * 512;
            unsigned* gc = (unsigned*)(ws + OFF_COFF) + ((b << 5) + c) * 512;
            gc[tid] = run;
            run += gh[tid];
        }
        bincnt[tid] = run;
        tot[tid] = run;
    }
    __syncthreads();
    for (int o = 1; o < 512; o <<= 1) {
        unsigned v = 0;
        if (tid < 512 && tid >= o) v = tot[tid - o];
        __syncthreads();
        if (tid < 512 && tid >= o) tot[tid] += v;
        __syncthreads();
    }
    if (tid < 512) {
        unsigned Pex = tot[tid] - bincnt[tid];
        unsigned* gp = (unsigned*)(ws + OFF_PRE) + b * 520;
        gp[tid] = Pex;
        if (tid == 511) gp[512] = tot[511];   // == NN
        for (int c = 0; c < 32; ++c) {
            unsigned* gc = (unsigned*)(ws + OFF_COFF) + ((b << 5) + c) * 512;
            gc[tid] += Pex;
        }
    }
}

// pass 3 (256 blocks): write digest sorted by (pol, y)
__global__ __launch_bounds__(1024) void sortwrite_kernel(const float* __restrict__ ev, float* __restrict__ ws) {
    int b = blockIdx.x >> 5, c = blockIdx.x & 31;
    const float* ex = ev + (size_t)b * 4 * NN;
    const float* ey = ex + NN;
    const float* et = ex + 2 * NN;
    const float* ep = ex + 3 * NN;
    __shared__ unsigned cur[512];
    const unsigned* gc = (const unsigned*)(ws + OFF_COFF) + ((b << 5) + c) * 512;
    for (int i = threadIdx.x; i < 512; i += 1024) cur[i] = gc[i];
    __syncthreads();
    float a = et[0];
    uint2* dg = (uint2*)(ws + OFF_DG) + (size_t)b * NN;
    int start = c * CH32, end = min(start + CH32, NN);
    for (int n = start + threadIdx.x; n < end; n += 1024) {
        float x = ex[n], y = ey[n], tt = et[n], p = ep[n];
        int yv = (int)y;
        int pol = (p == 1.0f) ? 0 : 1;
        unsigned idx = atomicAdd(&cur[(pol << 8) + yv], 1u);
        uint2 d;
        d.x = __float_as_uint(tt - a);
        d.y = (unsigned)(int)x | ((unsigned)yv << 8) | ((unsigned)pol << 16);
        dg[idx] = d;
    }
}

// pass 4 (512 blocks): scatter, batch = blockIdx&7, tile = blockIdx>>3 in [0,64).
// ALL scales y-banded with exact guard-limited scan ranges (balanced makespan):
//  [0,8)   s0: (pol,sgn) x 2 halves, 16 rows x 32
//  [8,16)  s1: (pol,sgn) x 2 halves, 32 rows x 64
//  [16,32) s2: (pol,sgn) x 4 bands, 32 rows x 128
//  [32,64) s3: (pol,sgn) x 8 bands, 32 rows x 256
// LDS-privatized tile, fused in-block reduce, ONE float atomic out.
__global__ __launch_bounds__(1024) void scatter_kernel(const float* __restrict__ f0,
                            const float* __restrict__ f1, const float* __restrict__ f2,
                            const float* __restrict__ f3, float* __restrict__ ws,
                            float* __restrict__ out) {
    __shared__ unsigned long long lds[8192];   // 64 KB max (s3 band)
    unsigned* cnts = (unsigned*)(ws + OFF_SUMS);
    int b    = blockIdx.x & 7;
    int tile = blockIdx.x >> 3;
    int tid  = threadIdx.x;
    int scale, c4, lo, nrows, w, sh;
    const float* fl;
    if (tile < 8)       {                  scale = 0; c4 = tile & 3;  lo = (tile >> 2) * 16; nrows = 16; w = 32;  sh = 3; fl = f0; }
    else if (tile < 16) { int g = tile - 8;  scale = 1; c4 = g & 3; lo = (g >> 2) * 32; nrows = 32; w = 64;  sh = 2; fl = f1; }
    else if (tile < 32) { int g = tile - 16; scale = 2; c4 = g & 3; lo = (g >> 2) * 32; nrows = 32; w = 128; sh = 1; fl = f2; }
    else                { int g = tile - 32; scale = 3; c4 = g & 3; lo = (g >> 2) * 32; nrows = 32; w = 256; sh = 0; fl = f3; }
    int pol = c4 >> 1, sgn = c4 & 1;
    int hw = w * w;
    int ncell = nrows * w;

    for (int i = tid; i < ncell / 2; i += 1024)
        ((ulonglong2*)lds)[i] = make_ulonglong2(0ULL, 0ULL);
    __syncthreads();

    const float* pp = ws + OFF_PARAMS + b * 32;
    float a    = pp[0];
    float invP = pp[1 + scale];
    float edge = (sgn == 0) ? (pp[7 + pol] - a) : (pp[5 + pol] - a);
    float base_t = edge * invP + ((sgn == 0) ? EPSF : -EPSF);
    fl += (size_t)b * 2 * hw;

    int G = (int)pp[10 + scale];
    int ylo = max((lo - G) << sh, 0);
    int yhi = min(((lo + nrows - 1 + G) << sh) + ((1 << sh) - 1), 255);
    const unsigned* gp = (const unsigned*)(ws + OFF_PRE) + b * 520 + (pol << 8);
    int r0 = (int)gp[ylo], r1 = (int)gp[yhi + 1];

    const uint2* dg = ((const uint2*)(ws + OFF_DG)) + (size_t)b * NN;
    float wm1 = (float)(w - 1);

    for (int n = r0 + tid; n < r1; n += 1024) {
        uint2 d = dg[n];
        float tb = __uint_as_float(d.x);
        int xi = (int)(d.y & 255u) >> sh;
        int yi = (int)((d.y >> 8) & 255u) >> sh;
        float fx = fl[yi * w + xi];
        float fy = fl[hw + yi * w + xi];
        float t_ = base_t - tb * invP;
        float x_ = fminf(fmaxf((float)xi + t_ * fx, 0.0f), wm1);
        float y_ = fminf(fmaxf((float)yi + t_ * fy, 0.0f), wm1);
        float x0 = floorf(x_), x1 = ceilf(x_);
        float y0 = floorf(y_), y1 = ceilf(y_);
        float x0r = 1.0f - (x_ - x0), x1r = 1.0f - (x1 - x_);
        float y0r = 1.0f - (y_ - y0), y1r = 1.0f - (y1 - y_);
        int ix0 = (int)x0, ix1 = (int)x1;
        int rr0 = (int)y0 - lo, rr1 = (int)y1 - lo;
        if (rr0 >= 0 && rr0 < nrows) {
            atomicAdd(&lds[rr0 * w + ix0], encq((x0r * y0r + EPSF) * t_));
            atomicAdd(&lds[rr0 * w + ix1], encq((x1r * y0r + EPSF) * t_));
        }
        if (rr1 >= 0 && rr1 < nrows) {
            atomicAdd(&lds[rr1 * w + ix0], encq((x0r * y1r + EPSF) * t_));
            atomicAdd(&lds[rr1 * w + ix1], encq((x1r * y1r + EPSF) * t_));
        }
    }
    __syncthreads();

    float acc = 0.0f;
    for (int i = tid; i < ncell; i += 1024) {
        unsigned long long A = lds[i];
        if (!A) continue;
        unsigned long long cnt = (A + (1ULL << 39)) >> 40;
        long long sq = (long long)(A - (cnt << 40));
        float num = (float)sq * QINV;
        float v = num / ((float)cnt + EPSF);
        acc += v * v;
    }
    float r = block_reduce_sum(acc);

    if (tid == 0) {
        atomicAdd(ws + OFF_SUMS, r);
        __threadfence();
        unsigned old = atomicAdd(&cnts[2], 1u);
        if (old == SC_TOT - 1) {
            float evl = atomicAdd(ws + OFF_SUMS, 0.0f);
            float sm  = atomicAdd(ws + OFF_SUMS + 1, 0.0f);
            out[0] = evl + sm;
            out[1] = evl;
            out[2] = sm;
        }
    }
}

extern "C" void kernel_launch(void* const* d_in, const int* in_sizes, int n_in,
                              void* d_out, int out_size, void* d_ws, size_t ws_size,
                              hipStream_t stream) {
    const float* ev = (const float*)d_in[0];
    const float* f0 = (const float*)d_in[1];
    const float* f1 = (const float*)d_in[2];
    const float* f2 = (const float*)d_in[3];
    const float* f3 = (const float*)d_in[4];
    float* ws  = (float*)d_ws;
    float* out = (float*)d_out;

    // zero sums + counter (512 B at float offset 256)
    hipMemsetAsync((char*)d_ws + OFF_SUMS * sizeof(float), 0, 512, stream);
    pass1_kernel<<<544, 1024, 0, stream>>>(ev, f0, f1, f2, f3, ws);
    prefix_kernel<<<BB, 1024, 0, stream>>>(ev, ws);
    sortwrite_kernel<<<256, 1024, 0, stream>>>(ev, ws);
    scatter_kernel<<<SC_TOT, 1024, 0, stream>>>(f0, f1, f2, f3, ws, out);
}